// Round 9
// baseline (230.303 us; speedup 1.0000x reference)
//
#include <hip/hip_runtime.h>
#include <hip/hip_bf16.h>

#define SEQ 2048
#define DM  1024
#define NH  16
#define HD  64
#define BH  32
#define QB  64            // q rows per block (2 q-halves x 32)
#define KVB 128           // keys per tile; 4 kv-quarter waves x 32
#define NT  (SEQ/KVB)     // 16 tiles
#define TILE_E (KVB*HD)   // 8192 bf16 per tile

#define KWS_OFF 0u        // [BH][NT][128 key][64 d]  swizzle baked
#define VWS_OFF 4194304u  // [BH][NT][64 d][128 kv]   transposed, swizzle baked

typedef __bf16 bf16x8 __attribute__((ext_vector_type(8)));
typedef float  f32x16 __attribute__((ext_vector_type(16)));
typedef unsigned int u32;

#define LOG2E 1.44269504088896f

// ---- prep: K/V fp32 -> bf16 head-split 128-key tiles, V transposed, swizzle baked ----
__global__ __launch_bounds__(256) void psa_prep(
    const float* __restrict__ V, const float* __restrict__ K,
    __bf16* __restrict__ ws)
{
    const int blk = blockIdx.x;
    if (blk < 2048) {
        // K chunk (bh, t, key, cb): K[b][t*128+key][h*64+d0..+7], d0=((cb^(key&7))<<3)
        const int idx = blk * 256 + threadIdx.x;
        const int cb = idx & 7, key = (idx >> 3) & 127, t = (idx >> 10) & 15, bh = idx >> 14;
        const int b = bh >> 4, h = bh & 15;
        const int d0 = ((cb ^ (key & 7)) << 3);
        const float* src = K + ((size_t)(b * SEQ + t * KVB + key)) * DM + h * HD + d0;
        float4 a = *(const float4*)src, c = *(const float4*)(src + 4);
        bf16x8 o;
        o[0] = (__bf16)a.x; o[1] = (__bf16)a.y; o[2] = (__bf16)a.z; o[3] = (__bf16)a.w;
        o[4] = (__bf16)c.x; o[5] = (__bf16)c.y; o[6] = (__bf16)c.z; o[7] = (__bf16)c.w;
        *(bf16x8*)(ws + KWS_OFF + (size_t)idx * 8) = o;
    } else {
        // V chunk (bh, t, d, cb): V[b][t*128+kv0+j][h*64+d], kv0=((cb^(d&7))<<3), cb in [0,16)
        const int idx = (blk - 2048) * 256 + threadIdx.x;
        const int cb = idx & 15, d = (idx >> 4) & 63, t = (idx >> 10) & 15, bh = idx >> 14;
        const int b = bh >> 4, h = bh & 15;
        const int kv0 = ((cb ^ (d & 7)) << 3);
        const float* src = V + ((size_t)(b * SEQ + t * KVB + kv0)) * DM + h * HD + d;
        bf16x8 o;
#pragma unroll
        for (int j = 0; j < 8; ++j) o[j] = (__bf16)src[(size_t)j * DM];
        *(bf16x8*)(ws + VWS_OFF + (size_t)idx * 8) = o;
    }
}

// ---- main: 8 waves = (q-half x kv-quarter), KVB=128 single-buffer, 32 waves/CU ----
__global__ __launch_bounds__(512, 8) void psa_main(
    const __bf16* __restrict__ ws, const float* __restrict__ Qg,
    float* __restrict__ Og)
{
    __shared__ __bf16 KT[TILE_E];         // 16 KB
    __shared__ __bf16 VT[TILE_E];         // 16 KB

    const int bid = blockIdx.x;
    const int swz = (bid & 7) * 128 + (bid >> 3);   // XCD-aware; 1024 % 8 == 0
    const int bh  = swz >> 5;
    const int qb  = swz & 31;
    const int b   = bh >> 4, h = bh & 15;
    const int tid = threadIdx.x;
    const int w   = tid >> 6;
    const int l   = tid & 63;
    const int q32 = l & 31;
    const int hi  = l >> 5;
    const int qh  = w & 1;                // q-half
    const int kvq = w >> 1;               // kv-quarter (0..3)
    const int q0  = qb * QB + qh * 32;

    const __bf16* Kws = ws + KWS_OFF;
    const __bf16* Vws = ws + VWS_OFF;

    // Q B-frags: lane holds col q=q0+q32, k-dim d = st*16 + hi*8 + j
    bf16x8 qf[4];
#pragma unroll
    for (int st = 0; st < 4; ++st) {
        const float* p = Qg + ((size_t)b * SEQ + q0 + q32) * DM + h * HD + st * 16 + hi * 8;
        float4 a = *(const float4*)p, c = *(const float4*)(p + 4);
        bf16x8 o;
        o[0] = (__bf16)a.x; o[1] = (__bf16)a.y; o[2] = (__bf16)a.z; o[3] = (__bf16)a.w;
        o[4] = (__bf16)c.x; o[5] = (__bf16)c.y; o[6] = (__bf16)c.z; o[7] = (__bf16)c.w;
        qf[st] = o;
    }

    f32x16 accd[2];
    f32x16 z16;
#pragma unroll
    for (int r = 0; r < 16; ++r) { accd[0][r] = 0.f; accd[1][r] = 0.f; z16[r] = 0.f; }

    auto stageK = [&](int t) {
        const size_t tb = ((size_t)bh * NT + t) * TILE_E;
#pragma unroll
        for (int i = 0; i < 2; ++i) {
            const int off = (i * 512 + tid) * 8;     // 1024 chunks of 16B
            __builtin_amdgcn_global_load_lds(
                (const __attribute__((address_space(1))) void*)(Kws + tb + off),
                (__attribute__((address_space(3))) void*)&KT[off], 16, 0, 0);
        }
    };
    auto stageV = [&](int t) {
        const size_t tb = ((size_t)bh * NT + t) * TILE_E;
#pragma unroll
        for (int i = 0; i < 2; ++i) {
            const int off = (i * 512 + tid) * 8;
            __builtin_amdgcn_global_load_lds(
                (const __attribute__((address_space(1))) void*)(Vws + tb + off),
                (__attribute__((address_space(3))) void*)&VT[off], 16, 0, 0);
        }
    };

    stageK(0);
    stageV(0);

    const int krow = kvq * 32 + q32;      // this wave's K rows (A-frag)
    for (int t = 0; t < NT; ++t) {
        asm volatile("s_waitcnt vmcnt(0)" ::: "memory");
        __builtin_amdgcn_s_barrier();                    // K(t), V(t) resident
        __builtin_amdgcn_sched_barrier(0);

        // ---- QK^T (A=K quarter, B=Q half) -> s
        bf16x8 af[4];
#pragma unroll
        for (int st = 0; st < 4; ++st)
            af[st] = *(const bf16x8*)&KT[krow * 64 +
                      ((st * 16 + hi * 8) ^ ((krow & 7) << 3))];
        __builtin_amdgcn_s_setprio(1);
        f32x16 s = __builtin_amdgcn_mfma_f32_32x32x16_bf16(af[0], qf[0], z16, 0, 0, 0);
        s = __builtin_amdgcn_mfma_f32_32x32x16_bf16(af[1], qf[1], s, 0, 0, 0);
        s = __builtin_amdgcn_mfma_f32_32x32x16_bf16(af[2], qf[2], s, 0, 0, 0);
        s = __builtin_amdgcn_mfma_f32_32x32x16_bf16(af[3], qf[3], s, 0, 0, 0);
        __builtin_amdgcn_s_setprio(0);

        __builtin_amdgcn_sched_barrier(0);
        __builtin_amdgcn_s_barrier();                    // all QK LDS reads retired
        __builtin_amdgcn_sched_barrier(0);
        if (t + 1 < NT) stageK(t + 1);                   // overlaps silu + PV

        // ---- silu + pack (in-register P frags via cvt_pk + permlane32_swap)
        float sl[16];
#pragma unroll
        for (int r = 0; r < 16; ++r) {
            float x = s[r];
            float e;
            asm("v_exp_f32 %0, %1" : "=v"(e) : "v"(x * -LOG2E));
            sl[r] = x * __builtin_amdgcn_rcpf(1.f + e);
        }
        u32 pw[2][4];
#pragma unroll
        for (int hf = 0; hf < 2; ++hf) {
            const int sb = hf * 8;
            u32 A, B, C, D;
            asm("v_cvt_pk_bf16_f32 %0, %1, %2" : "=v"(A) : "v"(sl[sb + 0]), "v"(sl[sb + 1]));
            asm("v_cvt_pk_bf16_f32 %0, %1, %2" : "=v"(B) : "v"(sl[sb + 4]), "v"(sl[sb + 5]));
            asm("v_cvt_pk_bf16_f32 %0, %1, %2" : "=v"(C) : "v"(sl[sb + 2]), "v"(sl[sb + 3]));
            asm("v_cvt_pk_bf16_f32 %0, %1, %2" : "=v"(D) : "v"(sl[sb + 6]), "v"(sl[sb + 7]));
            asm("v_permlane32_swap_b32 %0, %1" : "+v"(A), "+v"(B));
            asm("v_permlane32_swap_b32 %0, %1" : "+v"(C), "+v"(D));
            pw[hf][0] = A; pw[hf][1] = C; pw[hf][2] = B; pw[hf][3] = D;
        }

        // ---- out += P * V  (A = P frags in regs, B = V quarter from VT)
#pragma unroll
        for (int db = 0; db < 2; ++db) {
            const int vrow = db * 32 + q32;
#pragma unroll
            for (int ks = 0; ks < 2; ++ks) {
                bf16x8 vf = *(const bf16x8*)&VT[vrow * 128 +
                             ((kvq * 32 + ks * 16 + hi * 8) ^ ((vrow & 7) << 3))];
                union { u32 u[4]; bf16x8 v; } pu;
                pu.u[0] = pw[ks][0]; pu.u[1] = pw[ks][1];
                pu.u[2] = pw[ks][2]; pu.u[3] = pw[ks][3];
                __builtin_amdgcn_s_setprio(1);
                accd[db] = __builtin_amdgcn_mfma_f32_32x32x16_bf16(pu.v, vf, accd[db], 0, 0, 0);
                __builtin_amdgcn_s_setprio(0);
            }
        }

        __builtin_amdgcn_sched_barrier(0);
        __builtin_amdgcn_s_barrier();                    // all PV V-reads retired
        __builtin_amdgcn_sched_barrier(0);
        if (t + 1 < NT) stageV(t + 1);                   // overlaps loop-back
    }

    // ---- 4-way kv reduction through freed LDS (interleaved, conflict-free) ----
    float* red = (float*)&KT[0];                         // 32 KB free now
    const int slot1 = ((w >> 2) << 1) | (w & 1);         // 4 slots x 2048 floats
    if ((w >> 1) & 1) {                                  // kvq odd writes
#pragma unroll
        for (int db = 0; db < 2; ++db)
#pragma unroll
            for (int r = 0; r < 16; ++r)
                red[slot1 * 2048 + (db * 16 + r) * 64 + l] = accd[db][r];
    }
    __syncthreads();
    if (!((w >> 1) & 1)) {                               // kvq even adds partner (w|2)
#pragma unroll
        for (int db = 0; db < 2; ++db)
#pragma unroll
            for (int r = 0; r < 16; ++r)
                accd[db][r] += red[slot1 * 2048 + (db * 16 + r) * 64 + l];
    }
    __syncthreads();
    if (w == 4 || w == 5) {                              // kvq==2 writes
#pragma unroll
        for (int db = 0; db < 2; ++db)
#pragma unroll
            for (int r = 0; r < 16; ++r)
                red[(w & 1) * 2048 + (db * 16 + r) * 64 + l] = accd[db][r];
    }
    __syncthreads();
    if (w < 2) {                                         // kvq==0 adds + stores
#pragma unroll
        for (int db = 0; db < 2; ++db)
#pragma unroll
            for (int r = 0; r < 16; ++r)
                accd[db][r] += red[(w & 1) * 2048 + (db * 16 + r) * 64 + l];
        // D layout: row q = m*8 + r + hi*4, col d = db*32 + q32 (coalesced)
        float* op = Og + ((size_t)b * SEQ + q0) * DM + h * HD;
#pragma unroll
        for (int db = 0; db < 2; ++db)
#pragma unroll
            for (int m = 0; m < 4; ++m)
#pragma unroll
                for (int r = 0; r < 4; ++r)
                    op[(size_t)(m * 8 + r + hi * 4) * DM + db * 32 + q32] = accd[db][m * 4 + r];
    }
}

extern "C" void kernel_launch(void* const* d_in, const int* in_sizes, int n_in,
                              void* d_out, int out_size, void* d_ws, size_t ws_size,
                              hipStream_t stream) {
    const float* v = (const float*)d_in[0];
    const float* k = (const float*)d_in[1];
    const float* q = (const float*)d_in[2];
    float* out = (float*)d_out;
    __bf16* ws = (__bf16*)d_ws;
    (void)in_sizes; (void)n_in; (void)out_size; (void)ws_size;

    psa_prep<<<dim3(4096), dim3(256), 0, stream>>>(v, k, ws);
    psa_main<<<dim3(BH * (SEQ / QB)), dim3(512), 0, stream>>>(ws, q, out);
}

// Round 10
// 69.982 us; speedup vs baseline: 3.2909x; 3.2909x over previous
//
#include <hip/hip_runtime.h>
#include <hip/hip_bf16.h>

#define SEQ 2048
#define DM  1024
#define NH  16
#define HD  64
#define BH  32
#define QB  64            // q rows per block; 4 waves = (q-half x kv-half)
#define KVB 64
#define NT  (SEQ/KVB)     // 32 tiles
#define TILE_E (KVB*HD)   // 4096 bf16 per K tile

#define KWS_OFF 0u        // [BH][NT][64 key][64 d]        swizzle baked (LDS-staged)
#define VWS_OFF 4194304u  // [BH][NT][kvh][db][ks][64 lane][8]  V fragment-linear (reg-loaded)

typedef __bf16 bf16x8 __attribute__((ext_vector_type(8)));
typedef float  f32x16 __attribute__((ext_vector_type(16)));
typedef unsigned int u32;

#define LOG2E 1.44269504088896f

// ---- prep: K swizzled rows (for LDS DMA); V in per-wave fragment-linear layout ----
__global__ __launch_bounds__(256) void psa_prep(
    const float* __restrict__ V, const float* __restrict__ K,
    __bf16* __restrict__ ws)
{
    const int blk = blockIdx.x;
    if (blk < 2048) {
        // K chunk (bh, t, key, cb): K[b][t*64+key][h*64+d0..+7], d0=((cb^(key&7))<<3)
        const int idx = blk * 256 + threadIdx.x;
        const int cb = idx & 7, key = (idx >> 3) & 63, t = (idx >> 9) & 31, bh = idx >> 14;
        const int b = bh >> 4, h = bh & 15;
        const int d0 = ((cb ^ (key & 7)) << 3);
        const float* src = K + ((size_t)(b * SEQ + t * 64 + key)) * DM + h * HD + d0;
        float4 a = *(const float4*)src, c = *(const float4*)(src + 4);
        bf16x8 o;
        o[0] = (__bf16)a.x; o[1] = (__bf16)a.y; o[2] = (__bf16)a.z; o[3] = (__bf16)a.w;
        o[4] = (__bf16)c.x; o[5] = (__bf16)c.y; o[6] = (__bf16)c.z; o[7] = (__bf16)c.w;
        *(bf16x8*)(ws + KWS_OFF + (size_t)idx * 8) = o;
    } else {
        // V fragment chunk (bh, t, kvh, db, ks, lane):
        // elem j = V[b][t*64 + kvh*32 + ks*16 + (lane>>5)*8 + j][h*64 + db*32 + (lane&31)]
        const int idx = (blk - 2048) * 256 + threadIdx.x;
        const int lane = idx & 63, ks = (idx >> 6) & 1, db = (idx >> 7) & 1;
        const int kvh = (idx >> 8) & 1, t = (idx >> 9) & 31, bh = idx >> 14;
        const int b = bh >> 4, h = bh & 15;
        const int key0 = t * 64 + kvh * 32 + ks * 16 + (lane >> 5) * 8;
        const int col  = h * HD + db * 32 + (lane & 31);
        const float* src = V + (size_t)(b * SEQ + key0) * DM + col;
        bf16x8 o;
#pragma unroll
        for (int j = 0; j < 8; ++j) o[j] = (__bf16)src[(size_t)j * DM];
        *(bf16x8*)(ws + VWS_OFF + (size_t)idx * 8) = o;
    }
}

// ---- main: 4 waves (q-half x kv-half); K via LDS DMA dbuf (1 barrier/tile);
//      V direct global->reg, issued a full tile early (latency hidden) ----
__global__ __launch_bounds__(256, 4) void psa_main(
    const __bf16* __restrict__ ws, const float* __restrict__ Qg,
    float* __restrict__ Og)
{
    __shared__ __bf16 KT[2][TILE_E];      // 8 KB x2 — only K staged

    const int bid = blockIdx.x;
    const int swz = (bid & 7) * 128 + (bid >> 3);   // XCD-aware; 1024 % 8 == 0
    const int bh  = swz >> 5;
    const int qb  = swz & 31;
    const int b   = bh >> 4, h = bh & 15;
    const int tid = threadIdx.x;
    const int w   = tid >> 6;
    const int l   = tid & 63;
    const int q32 = l & 31;
    const int hi  = l >> 5;
    const int qh  = w & 1;                // q-half
    const int kvh = w >> 1;               // kv-half
    const int q0  = qb * QB + qh * 32;

    const __bf16* Kws = ws + KWS_OFF;
    const __bf16* vb  = ws + VWS_OFF + (size_t)bh * NT * 4096 + kvh * 2048 + l * 8;

    // Q B-frags: lane holds col q=q0+q32, k-dim d = st*16 + hi*8 + j
    bf16x8 qf[4];
#pragma unroll
    for (int st = 0; st < 4; ++st) {
        const float* p = Qg + ((size_t)b * SEQ + q0 + q32) * DM + h * HD + st * 16 + hi * 8;
        float4 a = *(const float4*)p, c = *(const float4*)(p + 4);
        bf16x8 o;
        o[0] = (__bf16)a.x; o[1] = (__bf16)a.y; o[2] = (__bf16)a.z; o[3] = (__bf16)a.w;
        o[4] = (__bf16)c.x; o[5] = (__bf16)c.y; o[6] = (__bf16)c.z; o[7] = (__bf16)c.w;
        qf[st] = o;
    }

    f32x16 accd[2];
#pragma unroll
    for (int r = 0; r < 16; ++r) { accd[0][r] = 0.f; accd[1][r] = 0.f; }

    auto stageK = [&](int bf, int t) {
        const size_t tb = ((size_t)bh * NT + t) * TILE_E;
#pragma unroll
        for (int i = 0; i < 2; ++i) {
            const int off = (i * 256 + tid) * 8;     // 512 chunks of 16B
            __builtin_amdgcn_global_load_lds(
                (const __attribute__((address_space(1))) void*)(Kws + tb + off),
                (__attribute__((address_space(3))) void*)&KT[bf][off], 16, 0, 0);
        }
    };

    const int krow = kvh * 32 + q32;      // this wave's K rows (A-frag)

    auto tile = [&](int t, bf16x8 (&vcur)[4], bf16x8 (&vnxt)[4]) {
        const int cur = t & 1;
        // stageK(t) is the oldest outstanding VMEM (2 ops); 4 V-loads newer stay in flight
        asm volatile("s_waitcnt vmcnt(4)" ::: "memory");
        __builtin_amdgcn_s_barrier();                // raw: no compiler drain
        __builtin_amdgcn_sched_barrier(0);
        if (t + 1 < NT) {
            stageK(cur ^ 1, t + 1);                  // 2 DMA loads (issued first)
#pragma unroll
            for (int j = 0; j < 4; ++j)              // 4 V frag loads (newer)
                vnxt[j] = *(const bf16x8*)(vb + (size_t)(t + 1) * 4096 + j * 512);
        }
        __builtin_amdgcn_sched_barrier(0);

        // ---- QK^T (A=K half, B=Q half)
        bf16x8 af[4];
#pragma unroll
        for (int st = 0; st < 4; ++st)
            af[st] = *(const bf16x8*)&KT[cur][krow * 64 +
                      ((st * 16 + hi * 8) ^ ((krow & 7) << 3))];
        __builtin_amdgcn_s_setprio(1);
        f32x16 s = __builtin_amdgcn_mfma_f32_32x32x16_bf16(af[0], qf[0], (f32x16){}, 0, 0, 0);
        s = __builtin_amdgcn_mfma_f32_32x32x16_bf16(af[1], qf[1], s, 0, 0, 0);
        s = __builtin_amdgcn_mfma_f32_32x32x16_bf16(af[2], qf[2], s, 0, 0, 0);
        s = __builtin_amdgcn_mfma_f32_32x32x16_bf16(af[3], qf[3], s, 0, 0, 0);
        __builtin_amdgcn_s_setprio(0);

        // ---- silu + pack (in-register P frags via cvt_pk + permlane32_swap)
        u32 pw[2][4];
#pragma unroll
        for (int hf = 0; hf < 2; ++hf) {
            float y[8];
#pragma unroll
            for (int r = 0; r < 8; ++r) {
                float x = s[hf * 8 + r];
                float e;
                asm("v_exp_f32 %0, %1" : "=v"(e) : "v"(x * -LOG2E));
                y[r] = x * __builtin_amdgcn_rcpf(1.f + e);
            }
            u32 A, B, C, D;
            asm("v_cvt_pk_bf16_f32 %0, %1, %2" : "=v"(A) : "v"(y[0]), "v"(y[1]));
            asm("v_cvt_pk_bf16_f32 %0, %1, %2" : "=v"(B) : "v"(y[4]), "v"(y[5]));
            asm("v_cvt_pk_bf16_f32 %0, %1, %2" : "=v"(C) : "v"(y[2]), "v"(y[3]));
            asm("v_cvt_pk_bf16_f32 %0, %1, %2" : "=v"(D) : "v"(y[6]), "v"(y[7]));
            asm("v_permlane32_swap_b32 %0, %1" : "+v"(A), "+v"(B));
            asm("v_permlane32_swap_b32 %0, %1" : "+v"(C), "+v"(D));
            pw[hf][0] = A; pw[hf][1] = C; pw[hf][2] = B; pw[hf][3] = D;
        }

        // ---- out += P * V  (A = P frags, B = V frags in regs; compiler waits vcur)
#pragma unroll
        for (int db = 0; db < 2; ++db) {
#pragma unroll
            for (int ks = 0; ks < 2; ++ks) {
                union { u32 u[4]; bf16x8 v; } pu;
                pu.u[0] = pw[ks][0]; pu.u[1] = pw[ks][1];
                pu.u[2] = pw[ks][2]; pu.u[3] = pw[ks][3];
                __builtin_amdgcn_s_setprio(1);
                accd[db] = __builtin_amdgcn_mfma_f32_32x32x16_bf16(
                    pu.v, vcur[db * 2 + ks], accd[db], 0, 0, 0);
                __builtin_amdgcn_s_setprio(0);
            }
        }
    };

    bf16x8 vfA[4], vfB[4];
    stageK(0, 0);
#pragma unroll
    for (int j = 0; j < 4; ++j)
        vfA[j] = *(const bf16x8*)(vb + j * 512);

    for (int t = 0; t < NT; t += 2) {
        tile(t,     vfA, vfB);
        tile(t + 1, vfB, vfA);
    }

    // ---- kv-half reduction through freed LDS (lane-contiguous, conflict-free)
    float* red = (float*)&KT[0][0];                  // 16 KB
    if (w >= 2) {                                    // kvh==1 writes
#pragma unroll
        for (int db = 0; db < 2; ++db)
#pragma unroll
            for (int r = 0; r < 16; ++r)
                red[(db * 16 + r) * 128 + qh * 64 + l] = accd[db][r];
    }
    __syncthreads();
    if (w < 2) {                                     // kvh==0 adds + stores
#pragma unroll
        for (int db = 0; db < 2; ++db)
#pragma unroll
            for (int r = 0; r < 16; ++r)
                accd[db][r] += red[(db * 16 + r) * 128 + qh * 64 + l];
        // D layout: row q = m*8 + r + hi*4, col d = db*32 + q32 (coalesced)
        float* op = Og + ((size_t)b * SEQ + q0) * DM + h * HD;
#pragma unroll
        for (int db = 0; db < 2; ++db)
#pragma unroll
            for (int m = 0; m < 4; ++m)
#pragma unroll
                for (int r = 0; r < 4; ++r)
                    op[(size_t)(m * 8 + r + hi * 4) * DM + db * 32 + q32] = accd[db][m * 4 + r];
    }
}

extern "C" void kernel_launch(void* const* d_in, const int* in_sizes, int n_in,
                              void* d_out, int out_size, void* d_ws, size_t ws_size,
                              hipStream_t stream) {
    const float* v = (const float*)d_in[0];
    const float* k = (const float*)d_in[1];
    const float* q = (const float*)d_in[2];
    float* out = (float*)d_out;
    __bf16* ws = (__bf16*)d_ws;
    (void)in_sizes; (void)n_in; (void)out_size; (void)ws_size;

    psa_prep<<<dim3(4096), dim3(256), 0, stream>>>(v, k, ws);
    psa_main<<<dim3(BH * (SEQ / QB)), dim3(256), 0, stream>>>(ws, q, out);
}

// Round 11
// 68.825 us; speedup vs baseline: 3.3462x; 1.0168x over previous
//
#include <hip/hip_runtime.h>
#include <hip/hip_bf16.h>

#define SEQ 2048
#define DM  1024
#define NH  16
#define HD  64
#define BH  32
#define QB  64            // q rows per block; 4 waves = (q-half x kv-half)
#define KVB 64
#define NT  (SEQ/KVB)     // 32 tiles
#define TILE_E (KVB*HD)   // 4096 bf16 per K tile

#define KWS_OFF 0u        // [BH][NT][64 key][64 d]            swizzle baked (LDS-staged)
#define VWS_OFF 4194304u  // [BH][NT][kvh][db][ks][64 lane][8] V fragment-linear (reg-loaded)

typedef __bf16 bf16x8 __attribute__((ext_vector_type(8)));
typedef float  f32x16 __attribute__((ext_vector_type(16)));
typedef unsigned int u32;

#define LOG2E 1.44269504088896f

// ---- prep: K swizzled rows (for LDS DMA); V in per-wave fragment-linear layout ----
__global__ __launch_bounds__(256) void psa_prep(
    const float* __restrict__ V, const float* __restrict__ K,
    __bf16* __restrict__ ws)
{
    const int blk = blockIdx.x;
    if (blk < 2048) {
        const int idx = blk * 256 + threadIdx.x;
        const int cb = idx & 7, key = (idx >> 3) & 63, t = (idx >> 9) & 31, bh = idx >> 14;
        const int b = bh >> 4, h = bh & 15;
        const int d0 = ((cb ^ (key & 7)) << 3);
        const float* src = K + ((size_t)(b * SEQ + t * 64 + key)) * DM + h * HD + d0;
        float4 a = *(const float4*)src, c = *(const float4*)(src + 4);
        bf16x8 o;
        o[0] = (__bf16)a.x; o[1] = (__bf16)a.y; o[2] = (__bf16)a.z; o[3] = (__bf16)a.w;
        o[4] = (__bf16)c.x; o[5] = (__bf16)c.y; o[6] = (__bf16)c.z; o[7] = (__bf16)c.w;
        *(bf16x8*)(ws + KWS_OFF + (size_t)idx * 8) = o;
    } else {
        // V frag chunk (bh, t, kvh, db, ks, lane):
        // elem j = V[b][t*64 + kvh*32 + ks*16 + (lane>>5)*8 + j][h*64 + db*32 + (lane&31)]
        const int idx = (blk - 2048) * 256 + threadIdx.x;
        const int lane = idx & 63, ks = (idx >> 6) & 1, db = (idx >> 7) & 1;
        const int kvh = (idx >> 8) & 1, t = (idx >> 9) & 31, bh = idx >> 14;
        const int b = bh >> 4, h = bh & 15;
        const int key0 = t * 64 + kvh * 32 + ks * 16 + (lane >> 5) * 8;
        const int col  = h * HD + db * 32 + (lane & 31);
        const float* src = V + (size_t)(b * SEQ + key0) * DM + col;
        bf16x8 o;
#pragma unroll
        for (int j = 0; j < 8; ++j) o[j] = (__bf16)src[(size_t)j * DM];
        *(bf16x8*)(ws + VWS_OFF + (size_t)idx * 8) = o;
    }
}

// ---- main: 4 waves (q-half x kv-half); K LDS dbuf, 1 barrier/tile;
//      one-tile pipeline: QK(t+1) MFMA overlaps silu(t) VALU ----
__global__ __launch_bounds__(256, 4) void psa_main(
    const __bf16* __restrict__ ws, const float* __restrict__ Qg,
    float* __restrict__ Og)
{
    __shared__ __bf16 KT[2][TILE_E];      // 8 KB x2 — only K staged

    const int bid = blockIdx.x;
    const int swz = (bid & 7) * 128 + (bid >> 3);   // XCD-aware; 1024 % 8 == 0
    const int bh  = swz >> 5;
    const int qb  = swz & 31;
    const int b   = bh >> 4, h = bh & 15;
    const int tid = threadIdx.x;
    const int w   = tid >> 6;
    const int l   = tid & 63;
    const int q32 = l & 31;
    const int hi  = l >> 5;
    const int qh  = w & 1;                // q-half
    const int kvh = w >> 1;               // kv-half
    const int q0  = qb * QB + qh * 32;

    const __bf16* Kws = ws + KWS_OFF;
    const __bf16* vb  = ws + VWS_OFF + (size_t)bh * NT * 4096 + kvh * 2048 + l * 8;

    // Q B-frags: lane holds col q=q0+q32, k-dim d = st*16 + hi*8 + j
    bf16x8 qf[4];
#pragma unroll
    for (int st = 0; st < 4; ++st) {
        const float* p = Qg + ((size_t)b * SEQ + q0 + q32) * DM + h * HD + st * 16 + hi * 8;
        float4 a = *(const float4*)p, c = *(const float4*)(p + 4);
        bf16x8 o;
        o[0] = (__bf16)a.x; o[1] = (__bf16)a.y; o[2] = (__bf16)a.z; o[3] = (__bf16)a.w;
        o[4] = (__bf16)c.x; o[5] = (__bf16)c.y; o[6] = (__bf16)c.z; o[7] = (__bf16)c.w;
        qf[st] = o;
    }

    f32x16 accd[2];
#pragma unroll
    for (int r = 0; r < 16; ++r) { accd[0][r] = 0.f; accd[1][r] = 0.f; }

    auto stageK = [&](int bf, int t) {
        const size_t tb = ((size_t)bh * NT + t) * TILE_E;
#pragma unroll
        for (int i = 0; i < 2; ++i) {
            const int off = (i * 256 + tid) * 8;     // 512 chunks of 16B
            __builtin_amdgcn_global_load_lds(
                (const __attribute__((address_space(1))) void*)(Kws + tb + off),
                (__attribute__((address_space(3))) void*)&KT[bf][off], 16, 0, 0);
        }
    };

    const int krow = kvh * 32 + q32;
    int koff[4];
#pragma unroll
    for (int st = 0; st < 4; ++st)
        koff[st] = krow * 64 + ((st * 16 + hi * 8) ^ ((krow & 7) << 3));

    auto qkt = [&](int cur) -> f32x16 {
        bf16x8 af0 = *(const bf16x8*)&KT[cur][koff[0]];
        bf16x8 af1 = *(const bf16x8*)&KT[cur][koff[1]];
        bf16x8 af2 = *(const bf16x8*)&KT[cur][koff[2]];
        bf16x8 af3 = *(const bf16x8*)&KT[cur][koff[3]];
        __builtin_amdgcn_s_setprio(1);
        f32x16 s = __builtin_amdgcn_mfma_f32_32x32x16_bf16(af0, qf[0], (f32x16){}, 0, 0, 0);
        s = __builtin_amdgcn_mfma_f32_32x32x16_bf16(af1, qf[1], s, 0, 0, 0);
        s = __builtin_amdgcn_mfma_f32_32x32x16_bf16(af2, qf[2], s, 0, 0, 0);
        s = __builtin_amdgcn_mfma_f32_32x32x16_bf16(af3, qf[3], s, 0, 0, 0);
        __builtin_amdgcn_s_setprio(0);
        return s;
    };

    // one tile body: silu+PV on sCur (tile t), QK(t+1) into sNext — overlapped
#define TILE_BODY(T, S_CUR, S_NXT)                                             \
    {                                                                          \
        const int t_ = (T);                                                    \
        asm volatile("s_waitcnt vmcnt(0)" ::: "memory");                       \
        __builtin_amdgcn_s_barrier();                                          \
        __builtin_amdgcn_sched_barrier(0);                                     \
        if (t_ + 2 < NT) stageK(t_ & 1, t_ + 2);                               \
        bf16x8 vf[4];                                                          \
        _Pragma("unroll")                                                      \
        for (int j = 0; j < 4; ++j)                                            \
            vf[j] = *(const bf16x8*)(vb + (size_t)t_ * 4096 + j * 512);        \
        if (t_ + 1 < NT) S_NXT = qkt((t_ + 1) & 1);                            \
        u32 pw[2][4];                                                          \
        _Pragma("unroll")                                                      \
        for (int hf = 0; hf < 2; ++hf) {                                       \
            float y[8];                                                        \
            _Pragma("unroll")                                                  \
            for (int r = 0; r < 8; ++r) {                                      \
                float x = S_CUR[hf * 8 + r];                                   \
                float e;                                                       \
                asm("v_exp_f32 %0, %1" : "=v"(e) : "v"(x * -LOG2E));           \
                y[r] = x * __builtin_amdgcn_rcpf(1.f + e);                     \
            }                                                                  \
            u32 A, B, C, D;                                                    \
            asm("v_cvt_pk_bf16_f32 %0, %1, %2" : "=v"(A) : "v"(y[0]), "v"(y[1])); \
            asm("v_cvt_pk_bf16_f32 %0, %1, %2" : "=v"(B) : "v"(y[4]), "v"(y[5])); \
            asm("v_cvt_pk_bf16_f32 %0, %1, %2" : "=v"(C) : "v"(y[2]), "v"(y[3])); \
            asm("v_cvt_pk_bf16_f32 %0, %1, %2" : "=v"(D) : "v"(y[6]), "v"(y[7])); \
            asm("v_permlane32_swap_b32 %0, %1" : "+v"(A), "+v"(B));            \
            asm("v_permlane32_swap_b32 %0, %1" : "+v"(C), "+v"(D));            \
            pw[hf][0] = A; pw[hf][1] = C; pw[hf][2] = B; pw[hf][3] = D;        \
        }                                                                      \
        union { u32 u[4]; bf16x8 v; } p0, p1;                                  \
        p0.u[0] = pw[0][0]; p0.u[1] = pw[0][1]; p0.u[2] = pw[0][2]; p0.u[3] = pw[0][3]; \
        p1.u[0] = pw[1][0]; p1.u[1] = pw[1][1]; p1.u[2] = pw[1][2]; p1.u[3] = pw[1][3]; \
        __builtin_amdgcn_s_setprio(1);                                         \
        accd[0] = __builtin_amdgcn_mfma_f32_32x32x16_bf16(p0.v, vf[0], accd[0], 0, 0, 0); \
        accd[0] = __builtin_amdgcn_mfma_f32_32x32x16_bf16(p1.v, vf[1], accd[0], 0, 0, 0); \
        accd[1] = __builtin_amdgcn_mfma_f32_32x32x16_bf16(p0.v, vf[2], accd[1], 0, 0, 0); \
        accd[1] = __builtin_amdgcn_mfma_f32_32x32x16_bf16(p1.v, vf[3], accd[1], 0, 0, 0); \
        __builtin_amdgcn_s_setprio(0);                                         \
    }

    f32x16 sA, sB;
    stageK(0, 0);
    stageK(1, 1);
    asm volatile("s_waitcnt vmcnt(2)" ::: "memory");   // K(0) resident; K(1) in flight
    __builtin_amdgcn_s_barrier();
    __builtin_amdgcn_sched_barrier(0);
    sA = qkt(0);

    for (int t = 0; t < NT; t += 2) {
        TILE_BODY(t,     sA, sB);
        TILE_BODY(t + 1, sB, sA);
    }
#undef TILE_BODY

    // ---- kv-half reduction through freed LDS (lane-contiguous, conflict-free)
    float* red = (float*)&KT[0][0];                  // 16 KB
    if (w >= 2) {                                    // kvh==1 writes
#pragma unroll
        for (int db = 0; db < 2; ++db)
#pragma unroll
            for (int r = 0; r < 16; ++r)
                red[(db * 16 + r) * 128 + qh * 64 + l] = accd[db][r];
    }
    __syncthreads();
    if (w < 2) {                                     // kvh==0 adds + stores
#pragma unroll
        for (int db = 0; db < 2; ++db)
#pragma unroll
            for (int r = 0; r < 16; ++r)
                accd[db][r] += red[(db * 16 + r) * 128 + qh * 64 + l];
        // D layout: row q = m*8 + r + hi*4, col d = db*32 + q32 (coalesced)
        float* op = Og + ((size_t)b * SEQ + q0) * DM + h * HD;
#pragma unroll
        for (int db = 0; db < 2; ++db)
#pragma unroll
            for (int m = 0; m < 4; ++m)
#pragma unroll
                for (int r = 0; r < 4; ++r)
                    op[(size_t)(m * 8 + r + hi * 4) * DM + db * 32 + q32] = accd[db][m * 4 + r];
    }
}

extern "C" void kernel_launch(void* const* d_in, const int* in_sizes, int n_in,
                              void* d_out, int out_size, void* d_ws, size_t ws_size,
                              hipStream_t stream) {
    const float* v = (const float*)d_in[0];
    const float* k = (const float*)d_in[1];
    const float* q = (const float*)d_in[2];
    float* out = (float*)d_out;
    __bf16* ws = (__bf16*)d_ws;
    (void)in_sizes; (void)n_in; (void)out_size; (void)ws_size;

    psa_prep<<<dim3(4096), dim3(256), 0, stream>>>(v, k, ws);
    psa_main<<<dim3(BH * (SEQ / QB)), dim3(256), 0, stream>>>(ws, q, out);
}